// Round 3
// 103.188 us; speedup vs baseline: 1.0731x; 1.0731x over previous
//
#include <hip/hip_runtime.h>
#include <math.h>

// x: (256, 224, 224) f32.  One block per row, whole row in registers.
#define HW   50176   // 224*224
#define NV4  12544   // float4 per row;  12544 = 12*1024 + 256
#define TPB  1024

typedef float floatx4 __attribute__((ext_vector_type(4)));

__device__ __forceinline__ float waveMin(float v) {
#pragma unroll
    for (int o = 32; o > 0; o >>= 1) v = fminf(v, __shfl_down(v, o, 64));
    return v;
}
__device__ __forceinline__ double waveSumD(double v) {
#pragma unroll
    for (int o = 32; o > 0; o >>= 1) v += __shfl_down(v, o, 64);
    return v;
}

__device__ __forceinline__ float digamma_f(float x) {
    // shift to >= 6, asymptotic series; matches jax digamma to ~1e-6
    float r = 0.0f;
#pragma unroll 6
    for (int i = 0; i < 6; ++i) {
        if (x < 6.0f) { r -= __fdividef(1.0f, x); x += 1.0f; }
    }
    float f = __fdividef(1.0f, x * x);
    float ser = f * (1.0f/12.0f - f * (1.0f/120.0f - f * (1.0f/252.0f - f * (1.0f/240.0f - f * (1.0f/132.0f)))));
    return r + __logf(x) - 0.5f * __fdividef(1.0f, x) - ser;
}
__device__ __forceinline__ float trigamma_ref(float x) {
    float z = x + 1.0f, zz = z * z;
    float a = 0.2f - __fdividef(1.0f, 7.0f * zz);
    float b = 1.0f - __fdividef(a, zz);
    float c = 1.0f + __fdividef(b, 3.0f * z);
    float d = 1.0f + __fdividef(c, 2.0f * z);
    return __fdividef(d, z) + __fdividef(1.0f, x * x);
}

__global__ void __launch_bounds__(TPB)
gamma_norm2d(const float* __restrict__ x, float* __restrict__ out) {
    const int row = blockIdx.x;
    const int tid = threadIdx.x;
    const float4* __restrict__ xr = (const float4*)(x + (size_t)row * HW);

    const bool extra = (tid < (NV4 - 12 * TPB));  // tid < 256 holds a 13th float4

    // ---- load entire row into registers (13 float4 / thread) ----
    float4 v[13];
#pragma unroll
    for (int j = 0; j < 12; ++j) v[j] = xr[tid + j * TPB];
    v[12] = extra ? xr[tid + 12 * TPB]
                  : make_float4(INFINITY, INFINITY, INFINITY, INFINITY);

    // ---- phase A: row min + raw sum ----
    float pmin = INFINITY, psum = 0.0f;
#pragma unroll
    for (int j = 0; j < 13; ++j) {
        pmin = fminf(pmin, fminf(fminf(v[j].x, v[j].y), fminf(v[j].z, v[j].w)));
        if (j < 12 || extra) psum += (v[j].x + v[j].y) + (v[j].z + v[j].w);
    }
    pmin = waveMin(pmin);
    double dsum = waveSumD((double)psum);

    __shared__ float  smin[16];
    __shared__ double sacc[16];
    __shared__ double ssl[16];
    __shared__ float  sparams[2];   // k, invth
    __shared__ float  scoef[8];

    const int wid = tid >> 6, lane = tid & 63;
    if (lane == 0) { smin[wid] = pmin; sacc[wid] = dsum; }
    __syncthreads();

    // all threads reduce the 16 wave-mins redundantly (kills a barrier + tid0 stall)
    float rmin = smin[0];
#pragma unroll
    for (int i = 1; i < 16; ++i) rmin = fminf(rmin, smin[i]);

    // ---- phase B: sum of ln(x - rmin + 2e-7) via quad-products ----
    // ln(a)+ln(b)+ln(c)+ln(d) = ln2 * log2((a*b)*(c*d)); values in (2e-7, 1]
    // so the quad product stays in [1.6e-27, 1] -- no under/overflow.
    const float C2 = rmin - 2e-7f;
    float psl = 0.0f;   // accumulates log2
#pragma unroll
    for (int j = 0; j < 13; ++j) {
        if (j < 12 || extra) {
            float a = v[j].x - C2, b = v[j].y - C2;
            float c = v[j].z - C2, d = v[j].w - C2;
            psl += __log2f((a * b) * (c * d));
        }
    }
    double dsl = waveSumD((double)psl);
    if (lane == 0) ssl[wid] = dsl;
    __syncthreads();

    // ---- per-row scalar solve (thread 0) ----
    if (tid == 0) {
        double ts = 0.0, tl2 = 0.0;
        for (int i = 0; i < 16; ++i) { ts += sacc[i]; tl2 += ssl[i]; }
        // shift: xm = x - rmin + 2e-7 (raw sum is linear in the shift)
        ts -= (double)HW * ((double)rmin - 2e-7);
        const double meand = ts / (double)HW;
        float s = logf((float)meand) - (float)(tl2 * 0.6931471805599453 / (double)HW);

        float s3 = s - 3.0f;
        float rt = sqrtf(s3 * s3 + 24.0f * s);
        float k  = __fdividef(3.0f - s + rt, 12.0f * s) + 1e-7f;
        // Minka init is ~1% accurate; Newton is quadratic -> f32 fixpoint by
        // iter 3-4; reference's iters 7-10 are identities. 6 keeps 2 spare.
#pragma unroll
        for (int it = 0; it < 6; ++it) {
            float nm = __logf(k) - digamma_f(k) - s;
            float dn = __fdividef(1.0f, k) - trigamma_ref(k);
            k -= __fdividef(nm, dn);
        }
        if (k < 1e-7f) k = 1e-7f;   // NaN falls through (np.clip semantics)
        if (k > 18.0f) k = 18.0f;

        // Lanczos Gamma(k): accumulator in f64 (cancellation), rest f32
        const double CH[8] = {676.5203681218851, -1259.1392167224028, 771.3234287776531,
                              -176.6150291621406, 12.507343278686905, -0.13857109526572012,
                              9.984369578019572e-06, 1.5056327351493116e-07};
        double acc = 0.9999999999998099;
#pragma unroll
        for (int i = 0; i < 8; ++i) acc += CH[i] / ((double)k + (double)(i + 1));
        float t  = k + 7.5f;
        float g  = __expf(fmaf(k + 0.5f, __logf(t), -t)) * 2.50662827463f * (float)acc / k; // Gamma(k)

        float den = g * k;                       // Gamma * k
        scoef[0] = __fdividef(1.0f, den);
#pragma unroll
        for (int j = 1; j < 8; ++j) {
            den *= (k + (float)j);
            scoef[j] = __fdividef(1.0f, den);
        }
        sparams[0] = k;
        sparams[1] = (float)((double)k / meand);   // 1/theta
    }
    __syncthreads();

    const float kk = sparams[0], invth = sparams[1];
    const float A  = invth;
    const float Bc = -(rmin - 1e-7f) * invth;      // xq = fma(x, A, Bc)
    const float c0 = scoef[0], c1 = scoef[1], c2 = scoef[2], c3 = scoef[3];
    const float c4 = scoef[4], c5 = scoef[5], c6 = scoef[6], c7 = scoef[7];
    const float NL2E = -1.4426950408889634f;       // -log2(e)

    // ---- phase C: y = 2^(k*log2(xq) - xq*log2e) * Horner(c, xq) ----
    floatx4* __restrict__ yr = (floatx4*)(out + (size_t)row * HW);
#pragma unroll
    for (int j = 0; j < 13; ++j) {
        if (j < 12 || extra) {
            float e[4] = {v[j].x, v[j].y, v[j].z, v[j].w};
            floatx4 o;
#pragma unroll
            for (int q = 0; q < 4; ++q) {
                float xq = fmaf(e[q], A, Bc);
                float p = fmaf(c7, xq, c6);
                p = fmaf(p, xq, c5);
                p = fmaf(p, xq, c4);
                p = fmaf(p, xq, c3);
                p = fmaf(p, xq, c2);
                p = fmaf(p, xq, c1);
                p = fmaf(p, xq, c0);
                float t2 = fmaf(kk, __log2f(xq), xq * NL2E);
                float y  = __builtin_amdgcn_exp2f(t2) * p;   // v_exp_f32 (base-2 native)
                o[q] = isfinite(y) ? y : 0.0f;
            }
            __builtin_nontemporal_store(o, yr + tid + j * TPB);
        }
    }
}

extern "C" void kernel_launch(void* const* d_in, const int* in_sizes, int n_in,
                              void* d_out, int out_size, void* d_ws, size_t ws_size,
                              hipStream_t stream) {
    const float* x = (const float*)d_in[0];
    float* out = (float*)d_out;
    const int rows = in_sizes[0] / HW;   // 256
    gamma_norm2d<<<dim3(rows), dim3(TPB), 0, stream>>>(x, out);
}